// Round 2
// baseline (5205.702 us; speedup 1.0000x reference)
//
#include <hip/hip_runtime.h>

typedef short bf16x8 __attribute__((ext_vector_type(8)));
typedef float f32x4 __attribute__((ext_vector_type(4)));

#define S_LEN 2048
#define NHQ 16
#define NKV 8
#define HD 256

__device__ __forceinline__ unsigned short f2bf(float f){
  unsigned u = __float_as_uint(f);
  unsigned r = (u + 0x7FFFu + ((u >> 16) & 1u)) >> 16;
  return (unsigned short)r;
}
__device__ __forceinline__ float bf2f(unsigned short h){
  return __uint_as_float(((unsigned)h) << 16);
}

// ---------------- elementwise f32 -> bf16 ----------------
__global__ void k_conv(const float* __restrict__ in, unsigned short* __restrict__ out, int n){
  int i = (blockIdx.x * 256 + threadIdx.x) * 4;
  if (i < n){
    float4 v = *(const float4*)&in[i];
    ushort4 o;
    o.x = f2bf(v.x); o.y = f2bf(v.y); o.z = f2bf(v.z); o.w = f2bf(v.w);
    *(ushort4*)&out[i] = o;
  }
}

// ---------------- tiled transpose + convert: in (R x C) f32 -> out (C x R) bf16 ----------------
__global__ void k_tconv(const float* __restrict__ in, unsigned short* __restrict__ out, int R, int C){
  __shared__ float tile[32][33];
  int c0 = blockIdx.x * 32, r0 = blockIdx.y * 32;
  int tx = threadIdx.x, ty = threadIdx.y;
  for (int i = 0; i < 4; i++)
    tile[ty + i*8][tx] = in[(size_t)(r0 + ty + i*8) * C + c0 + tx];
  __syncthreads();
  for (int i = 0; i < 4; i++)
    out[(size_t)(c0 + ty + i*8) * R + r0 + tx] = f2bf(tile[tx][ty + i*8]);
}

// ---------------- bf16 transpose for V: per (b,kv): (S x D) -> (D x S) ----------------
__global__ void k_vtrans(const unsigned short* __restrict__ V, unsigned short* __restrict__ VT){
  __shared__ unsigned short tile[32][40];
  int s0 = blockIdx.x * 32, d0 = blockIdx.y * 32, bz = blockIdx.z; // bz = b*NKV+kv
  int b = bz >> 3, kv = bz & 7;
  int tx = threadIdx.x, ty = threadIdx.y;
  for (int i = 0; i < 4; i++)
    tile[ty + i*8][tx] = V[(size_t)(b * S_LEN + s0 + ty + i*8) * (NKV*HD) + kv*HD + d0 + tx];
  __syncthreads();
  for (int i = 0; i < 4; i++)
    VT[((size_t)(bz * HD + d0 + ty + i*8)) * S_LEN + s0 + tx] = tile[tx][ty + i*8];
}

// ---------------- in-place RoPE on bf16 buffer (token, nh, 256) ----------------
__global__ void k_rope(unsigned short* buf, const float* __restrict__ cosb,
                       const float* __restrict__ sinb, int lgnh){
  int idx = blockIdx.x * 256 + threadIdx.x;
  int d = idx & 127;
  int h = (idx >> 7) & ((1 << lgnh) - 1);
  int t = idx >> (7 + lgnh);
  float c = cosb[t * 128 + d], s = sinb[t * 128 + d];
  size_t base = ((size_t)t << (lgnh + 8)) + ((size_t)h << 8) + d;
  float x1 = bf2f(buf[base]), x2 = bf2f(buf[base + 128]);
  buf[base]       = f2bf(x1 * c - x2 * s);
  buf[base + 128] = f2bf(x1 * s + x2 * c);
}

// ---------------- bf16 GEMM: C(MxN) = A(MxK) @ Bt(NxK)^T ; out f32 or bf16 ----------------
__global__ __launch_bounds__(256) void k_gemm_bt(const unsigned short* __restrict__ A,
    const unsigned short* __restrict__ Bt, void* __restrict__ Cp,
    int M, int N, int K, int out_bf16){
  __shared__ __align__(16) unsigned short As[128 * 64];
  __shared__ __align__(16) unsigned short Bs[128 * 64];
  int tid = threadIdx.x;
  int lane = tid & 63, wave = tid >> 6, quad = lane >> 4, l16 = lane & 15;
  int wm = wave >> 1, wn = wave & 1;
  int bm0 = blockIdx.y * 128, bn0 = blockIdx.x * 128;
  f32x4 acc[4][4] = {};
  for (int k0 = 0; k0 < K; k0 += 64){
    __syncthreads();
    for (int it = 0; it < 4; it++){
      int slot = it * 256 + tid;
      int row = slot >> 3, c = slot & 7;
      int pc = c ^ (row & 7);   // XOR-swizzled 16B chunks: conflict-free, no padding
      *(uint4*)&As[row * 64 + pc * 8] = *(const uint4*)&A[(size_t)(bm0 + row) * K + k0 + c * 8];
      *(uint4*)&Bs[row * 64 + pc * 8] = *(const uint4*)&Bt[(size_t)(bn0 + row) * K + k0 + c * 8];
    }
    __syncthreads();
    for (int ks = 0; ks < 2; ks++){
      bf16x8 af[4], bfr[4];
      for (int mt = 0; mt < 4; mt++){
        int row = wm * 64 + mt * 16 + l16;
        int pc = (ks * 4 + quad) ^ (row & 7);
        af[mt] = *(const bf16x8*)&As[row * 64 + pc * 8];
      }
      for (int nt = 0; nt < 4; nt++){
        int row = wn * 64 + nt * 16 + l16;
        int pc = (ks * 4 + quad) ^ (row & 7);
        bfr[nt] = *(const bf16x8*)&Bs[row * 64 + pc * 8];
      }
      for (int mt = 0; mt < 4; mt++)
        for (int nt = 0; nt < 4; nt++)
          acc[mt][nt] = __builtin_amdgcn_mfma_f32_16x16x32_bf16(af[mt], bfr[nt], acc[mt][nt], 0, 0, 0);
    }
  }
  for (int mt = 0; mt < 4; mt++){
    for (int nt = 0; nt < 4; nt++){
      for (int r = 0; r < 4; r++){
        int row = bm0 + wm * 64 + mt * 16 + quad * 4 + r;  // C/D: row=(lane>>4)*4+reg
        int col = bn0 + wn * 64 + nt * 16 + l16;           //      col=lane&15
        float v = acc[mt][nt][r];
        if (out_bf16) ((unsigned short*)Cp)[(size_t)row * N + col] = f2bf(v);
        else          ((float*)Cp)[(size_t)row * N + col] = v;
      }
    }
  }
}

// ---------------- flash attention ----------------
// Q (token, 16, 256) bf16 roped; K (token, 8, 256) bf16 roped; VT (b,kv,256,S) bf16
// Out (token, 16*256) bf16. grid (S/64, B*H), block 256 (4 waves x 16 q-rows)
__global__ __launch_bounds__(256) void k_flash(const unsigned short* __restrict__ Q,
    const unsigned short* __restrict__ Kg, const unsigned short* __restrict__ VTg,
    unsigned short* __restrict__ Og){
  __shared__ __align__(16) unsigned short Ks[32 * 264];   // 32 keys x (256+8)
  __shared__ __align__(16) unsigned short VTs[256 * 40];  // 256 d  x (32+8)
  __shared__ __align__(16) unsigned short Ps[4 * 16 * 40]; // per-wave 16 q x (32+8)
  int tid = threadIdx.x;
  int lane = tid & 63, wave = tid >> 6, quad = lane >> 4, l16 = lane & 15;
  int qt = blockIdx.x, hd_ = blockIdx.y;
  int b = hd_ >> 4, h = hd_ & 15, kv = h >> 1;

  // Q fragments in registers: wave handles q-rows [qt*64 + wave*16, +16)
  bf16x8 qf[8];
  {
    size_t qoff = ((size_t)(b * S_LEN + qt * 64 + wave * 16 + l16)) * (NHQ * HD) + (size_t)h * HD;
    for (int ks = 0; ks < 8; ks++)
      qf[ks] = *(const bf16x8*)&Q[qoff + ks * 32 + quad * 8];
  }
  f32x4 acc[16] = {};
  float mrow[4], lrow[4];
  for (int r = 0; r < 4; r++){ mrow[r] = -1e30f; lrow[r] = 0.f; }
  int qmin = qt * 64 + wave * 16;
  int nkt = qt * 2 + 2;
  const float L2E = 1.4426950408889634f;
  const float scale = 0.0625f; // 1/sqrt(256)

  for (int kt = 0; kt < nkt; kt++){
    __syncthreads();
    // cooperative staging: K tile (32x512B) + VT tile (256x64B)
    for (int it = 0; it < 4; it++){
      int slot = it * 256 + tid;
      int kr = slot >> 5, c = slot & 31;
      *(uint4*)&Ks[kr * 264 + c * 8] =
          *(const uint4*)&Kg[(size_t)(b * S_LEN + kt * 32 + kr) * (NKV*HD) + (size_t)kv * HD + c * 8];
      int dd = slot >> 2, c2 = slot & 3;
      *(uint4*)&VTs[dd * 40 + c2 * 8] =
          *(const uint4*)&VTg[((size_t)((b * NKV + kv) * HD + dd)) * S_LEN + kt * 32 + c2 * 8];
    }
    __syncthreads();
    if (kt * 32 > qmin + 15) continue;  // wave-uniform: tile fully above causal diag

    // S = Q @ K^T  (16 x 32 per wave)
    f32x4 sv[2] = {};
    for (int ks = 0; ks < 8; ks++){
      for (int nt = 0; nt < 2; nt++){
        bf16x8 kf = *(const bf16x8*)&Ks[(nt * 16 + l16) * 264 + ks * 32 + quad * 8];
        sv[nt] = __builtin_amdgcn_mfma_f32_16x16x32_bf16(qf[ks], kf, sv[nt], 0, 0, 0);
      }
    }
    // scale + causal mask + row max (rows = quad*4+r, cols = kt*32 + nt*16 + l16)
    float pv[2][4], tmax[4];
    for (int r = 0; r < 4; r++){
      int qr = qmin + quad * 4 + r;
      float mx = -1e30f;
      for (int nt = 0; nt < 2; nt++){
        int key = kt * 32 + nt * 16 + l16;
        float v = sv[nt][r] * scale;
        if (key > qr) v = -1e30f;
        pv[nt][r] = v;
        mx = fmaxf(mx, v);
      }
      tmax[r] = mx;
    }
    for (int off = 1; off < 16; off <<= 1)
      for (int r = 0; r < 4; r++)
        tmax[r] = fmaxf(tmax[r], __shfl_xor(tmax[r], off, 64));
    float alpha[4];
    for (int r = 0; r < 4; r++){
      float mn = fmaxf(mrow[r], tmax[r]);
      alpha[r] = exp2f((mrow[r] - mn) * L2E);
      mrow[r] = mn;
    }
    float pb[2][4], psum[4] = {0.f, 0.f, 0.f, 0.f};
    for (int nt = 0; nt < 2; nt++)
      for (int r = 0; r < 4; r++){
        float p = exp2f((pv[nt][r] - mrow[r]) * L2E);
        pb[nt][r] = p; psum[r] += p;
      }
    for (int off = 1; off < 16; off <<= 1)
      for (int r = 0; r < 4; r++)
        psum[r] += __shfl_xor(psum[r], off, 64);
    for (int r = 0; r < 4; r++) lrow[r] = lrow[r] * alpha[r] + psum[r];
    for (int i = 0; i < 16; i++)
      for (int r = 0; r < 4; r++) acc[i][r] *= alpha[r];
    // P: C-layout -> LDS -> A-layout (per-wave private, no barrier needed)
    int pbase = wave * 16 * 40;
    for (int nt = 0; nt < 2; nt++)
      for (int r = 0; r < 4; r++)
        Ps[pbase + (quad * 4 + r) * 40 + nt * 16 + l16] = f2bf(pb[nt][r]);
    bf16x8 pa = *(const bf16x8*)&Ps[pbase + l16 * 40 + quad * 8];
    // O += P @ V   (16 x 256 per wave)
    for (int nt = 0; nt < 16; nt++){
      bf16x8 vf = *(const bf16x8*)&VTs[(nt * 16 + l16) * 40 + quad * 8];
      acc[nt] = __builtin_amdgcn_mfma_f32_16x16x32_bf16(pa, vf, acc[nt], 0, 0, 0);
    }
  }
  float inv[4];
  for (int r = 0; r < 4; r++) inv[r] = 1.0f / lrow[r];
  size_t obase = ((size_t)(b * S_LEN + qt * 64 + wave * 16)) * (NHQ * HD) + (size_t)h * HD;
  for (int nt = 0; nt < 16; nt++)
    for (int r = 0; r < 4; r++)
      Og[obase + (size_t)(quad * 4 + r) * (NHQ * HD) + nt * 16 + l16] = f2bf(acc[nt][r] * inv[r]);
}

extern "C" void kernel_launch(void* const* d_in, const int* in_sizes, int n_in,
                              void* d_out, int out_size, void* d_ws, size_t ws_size,
                              hipStream_t stream){
  const float* hid  = (const float*)d_in[0];
  const float* cosb = (const float*)d_in[1];
  const float* sinb = (const float*)d_in[2];
  // d_in[3] = mask (causal, reconstructed analytically)
  const float* wq = (const float*)d_in[4];
  const float* wk = (const float*)d_in[5];
  const float* wv = (const float*)d_in[6];
  const float* wo = (const float*)d_in[7];

  char* ws = (char*)d_ws;
  size_t off = 0;
  auto alloc = [&](size_t bytes) -> void* {
    void* p = ws + off; off += (bytes + 255) & ~(size_t)255; return p;
  };
  unsigned short* Xbf = (unsigned short*)alloc(4096ull * 3072 * 2);
  unsigned short* WqT = (unsigned short*)alloc(4096ull * 3072 * 2);
  unsigned short* WkT = (unsigned short*)alloc(2048ull * 3072 * 2);
  unsigned short* WvT = (unsigned short*)alloc(2048ull * 3072 * 2);
  unsigned short* WoT = (unsigned short*)alloc(3072ull * 4096 * 2);
  unsigned short* Qb  = (unsigned short*)alloc(4096ull * 4096 * 2);
  unsigned short* Kb  = (unsigned short*)alloc(4096ull * 2048 * 2);
  unsigned short* Vb  = (unsigned short*)alloc(4096ull * 2048 * 2);
  unsigned short* VTb = (unsigned short*)alloc(4096ull * 2048 * 2);
  unsigned short* Ab  = (unsigned short*)alloc(4096ull * 4096 * 2);

  k_conv<<<12288, 256, 0, stream>>>(hid, Xbf, 4096 * 3072);
  k_tconv<<<dim3(128, 96), dim3(32, 8), 0, stream>>>(wq, WqT, 3072, 4096);
  k_tconv<<<dim3(64, 96),  dim3(32, 8), 0, stream>>>(wk, WkT, 3072, 2048);
  k_tconv<<<dim3(64, 96),  dim3(32, 8), 0, stream>>>(wv, WvT, 3072, 2048);
  k_tconv<<<dim3(96, 128), dim3(32, 8), 0, stream>>>(wo, WoT, 4096, 3072);
  k_gemm_bt<<<dim3(32, 32), 256, 0, stream>>>(Xbf, WqT, Qb, 4096, 4096, 3072, 1);
  k_gemm_bt<<<dim3(16, 32), 256, 0, stream>>>(Xbf, WkT, Kb, 4096, 2048, 3072, 1);
  k_gemm_bt<<<dim3(16, 32), 256, 0, stream>>>(Xbf, WvT, Vb, 4096, 2048, 3072, 1);
  k_rope<<<32768, 256, 0, stream>>>(Qb, cosb, sinb, 4);
  k_rope<<<16384, 256, 0, stream>>>(Kb, cosb, sinb, 3);
  k_vtrans<<<dim3(64, 8, 16), dim3(32, 8), 0, stream>>>(Vb, VTb);
  k_flash<<<dim3(32, 32), 256, 0, stream>>>(Qb, Kb, VTb, Ab);
  k_gemm_bt<<<dim3(24, 32), 256, 0, stream>>>(Ab, WoT, d_out, 4096, 3072, 4096, 0);
}

// Round 3
// 1055.980 us; speedup vs baseline: 4.9297x; 4.9297x over previous
//
#include <hip/hip_runtime.h>

typedef short bf16x8 __attribute__((ext_vector_type(8)));
typedef float f32x4 __attribute__((ext_vector_type(4)));

#define S_LEN 2048
#define NHQ 16
#define NKV 8
#define HD 256

__device__ __forceinline__ unsigned short f2bf(float f){
  unsigned u = __float_as_uint(f);
  unsigned r = (u + 0x7FFFu + ((u >> 16) & 1u)) >> 16;
  return (unsigned short)r;
}
__device__ __forceinline__ float bf2f(unsigned short h){
  return __uint_as_float(((unsigned)h) << 16);
}
__device__ __forceinline__ unsigned pack2(float a, float b){
  return (unsigned)f2bf(a) | ((unsigned)f2bf(b) << 16);
}

// ---------------- elementwise f32 -> bf16 ----------------
__global__ void k_conv(const float* __restrict__ in, unsigned short* __restrict__ out, int n){
  int i = (blockIdx.x * 256 + threadIdx.x) * 4;
  if (i < n){
    float4 v = *(const float4*)&in[i];
    ushort4 o;
    o.x = f2bf(v.x); o.y = f2bf(v.y); o.z = f2bf(v.z); o.w = f2bf(v.w);
    *(ushort4*)&out[i] = o;
  }
}

// ---------------- tiled transpose + convert: in (R x C) f32 -> out (C x R) bf16 ----------------
__global__ void k_tconv(const float* __restrict__ in, unsigned short* __restrict__ out, int R, int C){
  __shared__ float tile[32][33];
  int c0 = blockIdx.x * 32, r0 = blockIdx.y * 32;
  int tx = threadIdx.x, ty = threadIdx.y;
  for (int i = 0; i < 4; i++)
    tile[ty + i*8][tx] = in[(size_t)(r0 + ty + i*8) * C + c0 + tx];
  __syncthreads();
  for (int i = 0; i < 4; i++)
    out[(size_t)(c0 + ty + i*8) * R + r0 + tx] = f2bf(tile[tx][ty + i*8]);
}

// ---------------- bf16 transpose for V: per (b,kv): (S x D) -> (D x S) ----------------
__global__ void k_vtrans(const unsigned short* __restrict__ V, unsigned short* __restrict__ VT){
  __shared__ unsigned short tile[32][40];
  int s0 = blockIdx.x * 32, d0 = blockIdx.y * 32, bz = blockIdx.z; // bz = b*NKV+kv
  int b = bz >> 3, kv = bz & 7;
  int tx = threadIdx.x, ty = threadIdx.y;
  for (int i = 0; i < 4; i++)
    tile[ty + i*8][tx] = V[(size_t)(b * S_LEN + s0 + ty + i*8) * (NKV*HD) + kv*HD + d0 + tx];
  __syncthreads();
  for (int i = 0; i < 4; i++)
    VT[((size_t)(bz * HD + d0 + ty + i*8)) * S_LEN + s0 + tx] = tile[tx][ty + i*8];
}

// ---------------- in-place RoPE on bf16 buffer (token, nh, 256) ----------------
__global__ void k_rope(unsigned short* buf, const float* __restrict__ cosb,
                       const float* __restrict__ sinb, int lgnh){
  int idx = blockIdx.x * 256 + threadIdx.x;
  int d = idx & 127;
  int h = (idx >> 7) & ((1 << lgnh) - 1);
  int t = idx >> (7 + lgnh);
  float c = cosb[t * 128 + d], s = sinb[t * 128 + d];
  size_t base = ((size_t)t << (lgnh + 8)) + ((size_t)h << 8) + d;
  float x1 = bf2f(buf[base]), x2 = bf2f(buf[base + 128]);
  buf[base]       = f2bf(x1 * c - x2 * s);
  buf[base + 128] = f2bf(x1 * s + x2 * c);
}

// ---------------- bf16 GEMM: C(MxN) = A(MxK) @ Bt(NxK)^T ; out f32 or bf16 ----------------
__global__ __launch_bounds__(256) void k_gemm_bt(const unsigned short* __restrict__ A,
    const unsigned short* __restrict__ Bt, void* __restrict__ Cp,
    int M, int N, int K, int out_bf16){
  __shared__ __align__(16) unsigned short smem[2 * 128 * 64];  // 32 KB: As|Bs, reused as C-stage
  unsigned short* As = smem;
  unsigned short* Bs = smem + 128 * 64;
  int tid = threadIdx.x;
  int lane = tid & 63, wave = tid >> 6, quad = lane >> 4, l16 = lane & 15;
  int wm = wave >> 1, wn = wave & 1;
  int bm0 = blockIdx.y * 128, bn0 = blockIdx.x * 128;
  f32x4 acc[4][4] = {};
  for (int k0 = 0; k0 < K; k0 += 64){
    __syncthreads();
    for (int it = 0; it < 4; it++){
      int slot = it * 256 + tid;
      int row = slot >> 3, c = slot & 7;
      int pc = c ^ (row & 7);   // XOR-swizzled 16B chunks: conflict-free, no padding
      *(uint4*)&As[row * 64 + pc * 8] = *(const uint4*)&A[(size_t)(bm0 + row) * K + k0 + c * 8];
      *(uint4*)&Bs[row * 64 + pc * 8] = *(const uint4*)&Bt[(size_t)(bn0 + row) * K + k0 + c * 8];
    }
    __syncthreads();
    for (int ks = 0; ks < 2; ks++){
      bf16x8 af[4], bfr[4];
      for (int mt = 0; mt < 4; mt++){
        int row = wm * 64 + mt * 16 + l16;
        int pc = (ks * 4 + quad) ^ (row & 7);
        af[mt] = *(const bf16x8*)&As[row * 64 + pc * 8];
      }
      for (int nt = 0; nt < 4; nt++){
        int row = wn * 64 + nt * 16 + l16;
        int pc = (ks * 4 + quad) ^ (row & 7);
        bfr[nt] = *(const bf16x8*)&Bs[row * 64 + pc * 8];
      }
      for (int mt = 0; mt < 4; mt++)
        for (int nt = 0; nt < 4; nt++)
          acc[mt][nt] = __builtin_amdgcn_mfma_f32_16x16x32_bf16(af[mt], bfr[nt], acc[mt][nt], 0, 0, 0);
    }
  }
  // ---- coalesced epilogue: stage 64 rows of C at a time in LDS, store 16B/lane ----
  float* Ct = (float*)smem;  // 64 x 128 f32 = 32 KB
  for (int p = 0; p < 2; p++){
    __syncthreads();
    if (wm == p){
      for (int mt = 0; mt < 4; mt++)
        for (int nt = 0; nt < 4; nt++)
          for (int r = 0; r < 4; r++)
            Ct[(mt * 16 + quad * 4 + r) * 128 + wn * 64 + nt * 16 + l16] = acc[mt][nt][r];
    }
    __syncthreads();
    if (out_bf16){
      unsigned short* O = (unsigned short*)Cp;
      for (int j = 0; j < 4; j++){
        int chunk = j * 256 + tid;        // 1024 chunks x 8 elems
        int row = chunk >> 4, col = (chunk & 15) * 8;
        const float* src = &Ct[row * 128 + col];
        uint4 o;
        o.x = pack2(src[0], src[1]);
        o.y = pack2(src[2], src[3]);
        o.z = pack2(src[4], src[5]);
        o.w = pack2(src[6], src[7]);
        *(uint4*)&O[(size_t)(bm0 + p * 64 + row) * N + bn0 + col] = o;
      }
    } else {
      float* O = (float*)Cp;
      for (int j = 0; j < 8; j++){
        int chunk = j * 256 + tid;        // 2048 chunks x 4 elems
        int row = chunk >> 5, col = (chunk & 31) * 4;
        *(float4*)&O[(size_t)(bm0 + p * 64 + row) * N + bn0 + col] = *(const float4*)&Ct[row * 128 + col];
      }
    }
  }
}

// ---------------- flash attention ----------------
// Q (token, 16, 256) bf16 roped; K (token, 8, 256) bf16 roped; VT (b,kv,256,S) bf16
// Out (token, 16*256) bf16. grid (S/64, B*H), block 256 (4 waves x 16 q-rows)
__global__ __launch_bounds__(256) void k_flash(const unsigned short* __restrict__ Q,
    const unsigned short* __restrict__ Kg, const unsigned short* __restrict__ VTg,
    unsigned short* __restrict__ Og){
  __shared__ __align__(16) unsigned short smem[32 * 264 + 256 * 40 + 4 * 16 * 40];
  unsigned short* Ks  = smem;              // 32 keys x (256+8)
  unsigned short* VTs = smem + 32 * 264;   // 256 d x (32+8)
  unsigned short* Ps  = VTs + 256 * 40;    // per-wave 16 q x (32+8)
  int tid = threadIdx.x;
  int lane = tid & 63, wave = tid >> 6, quad = lane >> 4, l16 = lane & 15;
  int qt = blockIdx.x, hd_ = blockIdx.y;
  int b = hd_ >> 4, h = hd_ & 15, kv = h >> 1;

  // Q fragments in registers: wave handles q-rows [qt*64 + wave*16, +16)
  bf16x8 qf[8];
  {
    size_t qoff = ((size_t)(b * S_LEN + qt * 64 + wave * 16 + l16)) * (NHQ * HD) + (size_t)h * HD;
    for (int ks = 0; ks < 8; ks++)
      qf[ks] = *(const bf16x8*)&Q[qoff + ks * 32 + quad * 8];
  }
  f32x4 acc[16] = {};
  float mrow[4], lrow[4];
  for (int r = 0; r < 4; r++){ mrow[r] = -1e30f; lrow[r] = 0.f; }
  int qmin = qt * 64 + wave * 16;
  int nkt = qt * 2 + 2;
  const float L2E = 1.4426950408889634f;
  const float scale = 0.0625f; // 1/sqrt(256)

  for (int kt = 0; kt < nkt; kt++){
    __syncthreads();
    // cooperative staging: K tile (32x512B) + VT tile (256x64B)
    for (int it = 0; it < 4; it++){
      int slot = it * 256 + tid;
      int kr = slot >> 5, c = slot & 31;
      *(uint4*)&Ks[kr * 264 + c * 8] =
          *(const uint4*)&Kg[(size_t)(b * S_LEN + kt * 32 + kr) * (NKV*HD) + (size_t)kv * HD + c * 8];
      int dd = slot >> 2, c2 = slot & 3;
      *(uint4*)&VTs[dd * 40 + c2 * 8] =
          *(const uint4*)&VTg[((size_t)((b * NKV + kv) * HD + dd)) * S_LEN + kt * 32 + c2 * 8];
    }
    __syncthreads();
    if (kt * 32 > qmin + 15) continue;  // wave-uniform: tile fully above causal diag

    // S = Q @ K^T  (16 x 32 per wave)
    f32x4 sv[2] = {};
    for (int ks = 0; ks < 8; ks++){
      for (int nt = 0; nt < 2; nt++){
        bf16x8 kf = *(const bf16x8*)&Ks[(nt * 16 + l16) * 264 + ks * 32 + quad * 8];
        sv[nt] = __builtin_amdgcn_mfma_f32_16x16x32_bf16(qf[ks], kf, sv[nt], 0, 0, 0);
      }
    }
    // scale + causal mask + row max (rows = quad*4+r, cols = kt*32 + nt*16 + l16)
    float pv[2][4], tmax[4];
    for (int r = 0; r < 4; r++){
      int qr = qmin + quad * 4 + r;
      float mx = -1e30f;
      for (int nt = 0; nt < 2; nt++){
        int key = kt * 32 + nt * 16 + l16;
        float v = sv[nt][r] * scale;
        if (key > qr) v = -1e30f;
        pv[nt][r] = v;
        mx = fmaxf(mx, v);
      }
      tmax[r] = mx;
    }
    for (int off = 1; off < 16; off <<= 1)
      for (int r = 0; r < 4; r++)
        tmax[r] = fmaxf(tmax[r], __shfl_xor(tmax[r], off, 64));
    float alpha[4];
    for (int r = 0; r < 4; r++){
      float mn = fmaxf(mrow[r], tmax[r]);
      alpha[r] = exp2f((mrow[r] - mn) * L2E);
      mrow[r] = mn;
    }
    float pb[2][4], psum[4] = {0.f, 0.f, 0.f, 0.f};
    for (int nt = 0; nt < 2; nt++)
      for (int r = 0; r < 4; r++){
        float p = exp2f((pv[nt][r] - mrow[r]) * L2E);
        pb[nt][r] = p; psum[r] += p;
      }
    for (int off = 1; off < 16; off <<= 1)
      for (int r = 0; r < 4; r++)
        psum[r] += __shfl_xor(psum[r], off, 64);
    for (int r = 0; r < 4; r++) lrow[r] = lrow[r] * alpha[r] + psum[r];
    for (int i = 0; i < 16; i++)
      for (int r = 0; r < 4; r++) acc[i][r] *= alpha[r];
    // P: C-layout -> LDS -> A-layout (per-wave private, no barrier needed)
    int pbase = wave * 16 * 40;
    for (int nt = 0; nt < 2; nt++)
      for (int r = 0; r < 4; r++)
        Ps[pbase + (quad * 4 + r) * 40 + nt * 16 + l16] = f2bf(pb[nt][r]);
    bf16x8 pa = *(const bf16x8*)&Ps[pbase + l16 * 40 + quad * 8];
    // O += P @ V   (16 x 256 per wave)
    for (int nt = 0; nt < 16; nt++){
      bf16x8 vf = *(const bf16x8*)&VTs[(nt * 16 + l16) * 40 + quad * 8];
      acc[nt] = __builtin_amdgcn_mfma_f32_16x16x32_bf16(pa, vf, acc[nt], 0, 0, 0);
    }
  }
  // ---- coalesced epilogue: per-wave O tile (16 x 256 bf16) via LDS, 16B/lane stores ----
  float inv[4];
  for (int r = 0; r < 4; r++) inv[r] = 1.0f / lrow[r];
  __syncthreads();  // all waves done with Ks/VTs
  unsigned short* Ot = smem + wave * 16 * 256;  // 8 KB per wave
  for (int nt = 0; nt < 16; nt++)
    for (int r = 0; r < 4; r++)
      Ot[(quad * 4 + r) * 256 + nt * 16 + l16] = f2bf(acc[nt][r] * inv[r]);
  size_t obase = ((size_t)(b * S_LEN + qt * 64 + wave * 16)) * (NHQ * HD) + (size_t)h * HD;
  for (int j = 0; j < 8; j++){
    int chunk = j * 64 + lane;      // 512 chunks x 8 shorts
    int row = chunk >> 5, col = (chunk & 31) * 8;
    *(uint4*)&Og[obase + (size_t)row * (NHQ * HD) + col] = *(const uint4*)&Ot[row * 256 + col];
  }
}

extern "C" void kernel_launch(void* const* d_in, const int* in_sizes, int n_in,
                              void* d_out, int out_size, void* d_ws, size_t ws_size,
                              hipStream_t stream){
  const float* hid  = (const float*)d_in[0];
  const float* cosb = (const float*)d_in[1];
  const float* sinb = (const float*)d_in[2];
  // d_in[3] = mask (causal, reconstructed analytically)
  const float* wq = (const float*)d_in[4];
  const float* wk = (const float*)d_in[5];
  const float* wv = (const float*)d_in[6];
  const float* wo = (const float*)d_in[7];

  char* ws = (char*)d_ws;
  size_t off = 0;
  auto alloc = [&](size_t bytes) -> void* {
    void* p = ws + off; off += (bytes + 255) & ~(size_t)255; return p;
  };
  unsigned short* Xbf = (unsigned short*)alloc(4096ull * 3072 * 2);
  unsigned short* WqT = (unsigned short*)alloc(4096ull * 3072 * 2);
  unsigned short* WkT = (unsigned short*)alloc(2048ull * 3072 * 2);
  unsigned short* WvT = (unsigned short*)alloc(2048ull * 3072 * 2);
  unsigned short* WoT = (unsigned short*)alloc(3072ull * 4096 * 2);
  unsigned short* Qb  = (unsigned short*)alloc(4096ull * 4096 * 2);
  unsigned short* Kb  = (unsigned short*)alloc(4096ull * 2048 * 2);
  unsigned short* Vb  = (unsigned short*)alloc(4096ull * 2048 * 2);
  unsigned short* VTb = (unsigned short*)alloc(4096ull * 2048 * 2);
  unsigned short* Ab  = (unsigned short*)alloc(4096ull * 4096 * 2);

  k_conv<<<12288, 256, 0, stream>>>(hid, Xbf, 4096 * 3072);
  k_tconv<<<dim3(128, 96), dim3(32, 8), 0, stream>>>(wq, WqT, 3072, 4096);
  k_tconv<<<dim3(64, 96),  dim3(32, 8), 0, stream>>>(wk, WkT, 3072, 2048);
  k_tconv<<<dim3(64, 96),  dim3(32, 8), 0, stream>>>(wv, WvT, 3072, 2048);
  k_tconv<<<dim3(96, 128), dim3(32, 8), 0, stream>>>(wo, WoT, 4096, 3072);
  k_gemm_bt<<<dim3(32, 32), 256, 0, stream>>>(Xbf, WqT, Qb, 4096, 4096, 3072, 1);
  k_gemm_bt<<<dim3(16, 32), 256, 0, stream>>>(Xbf, WkT, Kb, 4096, 2048, 3072, 1);
  k_gemm_bt<<<dim3(16, 32), 256, 0, stream>>>(Xbf, WvT, Vb, 4096, 2048, 3072, 1);
  k_rope<<<32768, 256, 0, stream>>>(Qb, cosb, sinb, 4);
  k_rope<<<16384, 256, 0, stream>>>(Kb, cosb, sinb, 3);
  k_vtrans<<<dim3(64, 8, 16), dim3(32, 8), 0, stream>>>(Vb, VTb);
  k_flash<<<dim3(32, 32), 256, 0, stream>>>(Qb, Kb, VTb, Ab);
  k_gemm_bt<<<dim3(24, 32), 256, 0, stream>>>(Ab, WoT, d_out, 4096, 3072, 4096, 0);
}